// Round 13
// baseline (710.523 us; speedup 1.0000x reference)
//
#include <hip/hip_runtime.h>
#include <hip/hip_bf16.h>

// ROUND 13: r12 sync (proven) + GEMM restructure: 4 waves x 32 rows (256
// threads), ALL 48 W B-fragments in registers (192 VGPR; 1 wave/SIMD ->
// 512-VGPR budget), loaded once from global. ZERO LDS traffic in the GEMM
// t-loop (r12: 128 ds_read_b128 + ~520 conflict-cy per block per step on
// the inter-step critical chain). Pred block likewise 4 waves, U frags in
// registers. Sync/data-path primitives unchanged from r12.

// Problem constants
#define NB 1024      // batch
#define NT 120       // seq len
#define NE 50        // embed
#define NH 300       // hidden
#define KX 64        // padded x K (50 -> 64): k-chunks 0..1
#define KH 320       // padded h K (300 -> 320): k-chunks 2..11
#define KT 384       // total padded K (12 chunks of 32)
#define HP 320       // padded h-cols per gate in WpT
#define NGRP 8       // row groups of 128 rows; group = blk & 7 (XCD-aligned)
#define NCOLB 19     // GEMM workers per group (19*16 = 304 >= 300 hidden cols)
#define ROLES 20     // 19 GEMM + 1 pred
#define GRID 160     // 8 groups * 20 roles; blk = role*8 + g
#define HSLOTS 8     // h ring buffers; GEMM t gates pred-done(t-8)

typedef __bf16 bf16_t;
typedef __bf16 bf16x8 __attribute__((ext_vector_type(8)));
typedef float f32x4 __attribute__((ext_vector_type(4)));

// Fast gates via v_rcp_f32 (~1e-7 rel err, negligible vs bf16-h rounding).
__device__ __forceinline__ float fsig(float x) {
    return __builtin_amdgcn_rcpf(1.0f + __expf(-x));
}
__device__ __forceinline__ float ftanh(float x) {
    return fmaf(2.0f, __builtin_amdgcn_rcpf(1.0f + __expf(-2.0f * x)), -1.0f);
}

// ---- fallback (cross-XCD) transport: relaxed agent atomics (MALL) ----
__device__ __forceinline__ bf16x8 coh_load8(const bf16_t* p) {
    const unsigned long long* q = (const unsigned long long*)p;
    union { unsigned long long u[2]; bf16x8 v; } t;
    t.u[0] = __hip_atomic_load(q,     __ATOMIC_RELAXED, __HIP_MEMORY_SCOPE_AGENT);
    t.u[1] = __hip_atomic_load(q + 1, __ATOMIC_RELAXED, __HIP_MEMORY_SCOPE_AGENT);
    return t.v;
}
__device__ __forceinline__ void coh_store16(bf16_t* p, bf16_t h) {
    __hip_atomic_store((unsigned short*)p, __builtin_bit_cast(unsigned short, h),
                       __ATOMIC_RELAXED, __HIP_MEMORY_SCOPE_AGENT);
}
__device__ __forceinline__ unsigned coh_loadu(const unsigned* p) {
    return __hip_atomic_load(p, __ATOMIC_RELAXED, __HIP_MEMORY_SCOPE_AGENT);
}
// Counter bump: device-scope atomic add, result discarded (proven r12).
__device__ __forceinline__ void cnt_bump(unsigned* p) {
    __hip_atomic_fetch_add(p, 1u, __ATOMIC_RELAXED, __HIP_MEMORY_SCOPE_AGENT);
}

// ---- local (same-XCD) transport helpers (proven r5-r12) ----
__device__ __forceinline__ void inv_l1() {
    asm volatile("buffer_inv sc0\n\ts_waitcnt vmcnt(0)" ::: "memory");
}
__device__ __forceinline__ unsigned xcc_id() {
    unsigned x;
    asm volatile("s_getreg_b32 %0, hwreg(HW_REG_XCC_ID)" : "=s"(x));
    return x & 0xfu;
}

// ---------------- fused prep kernel (one launch) ----------------
__global__ void prep_all(const int* __restrict__ ids, const float* __restrict__ emb,
                         const float* __restrict__ W,
                         bf16_t* __restrict__ WpT, uint4* __restrict__ zbase,
                         int nzero, bf16_t* __restrict__ Xp) {
    const long stride = (long)gridDim.x * 256;
    const long g0 = (long)blockIdx.x * 256 + threadIdx.x;

    for (long i = g0; i < nzero; i += stride)
        zbase[i] = make_uint4(0u, 0u, 0u, 0u);

    for (long gid = g0; gid < 4 * HP * KT; gid += stride) {
        int k = (int)(gid % KT);
        int col = (int)(gid / KT);
        int g = col / HP, hc = col % HP;
        int kp = -1;
        if (k < 50) kp = k;
        else if (k >= 64 && k < 364) kp = k - 14;
        float v = 0.0f;
        if (kp >= 0 && hc < NH) v = W[(long)kp * 1200 + g * NH + hc];
        WpT[gid] = (bf16_t)v;
    }

    for (long gid = g0; gid < (long)NB * NT * 4; gid += stride) {
        int s = (int)(gid & 3);
        long bt = gid >> 2;
        int b = (int)(bt / NT), t = (int)(bt % NT);
        int id = ids[bt];
        const float* er = emb + (long)id * NE;
        bf16_t* dst = Xp + ((long)t * NB + b) * KX + s * 16;
#pragma unroll
        for (int j = 0; j < 16; ++j) {
            int e = s * 16 + j;
            dst[j] = (bf16_t)((e < NE) ? er[e] : 0.0f);
        }
    }
}

// ---------------- persistent LSTM kernel ----------------
// blk = role*8 + g. Roles 0..18: GEMM worker for hidden cols role*16..+15
// (all 4 gates) of group g (rows g*128..+127), 4 waves x 32 rows (2 tiles),
// full W slice (48 bf16x8 frags) in VGPRs. Role 19: pred block (MFMA
// h_t @ U, split-precision hi+lo U in VGPRs). h ring of 8 slots. Counters:
// agent fetch_add publish / single-lane agent atomic-load poll (r12-proven).
// Local mode: plain write-through h stores + one inv_l1 at wait-exit +
// plain L2 loads; fallback: MALL agent atomics.
__global__ void __launch_bounds__(256, 1) lstm_persist(
    const float* __restrict__ bl, const bf16_t* __restrict__ WpT,
    bf16_t* Hbase,
    const bf16_t* __restrict__ Xp,
    unsigned* gcnt, unsigned* pcnt, unsigned* xcdA,
    const float* __restrict__ U, const float* __restrict__ b2,
    float* __restrict__ out)
{
    __shared__ __align__(16) unsigned char smem[20608];   // pred U hi+lo staging
    __shared__ int sLocalOK;
    const int blk = blockIdx.x;
    const int tid = threadIdx.x;
    const int g = blk & 7;
    const int c = blk >> 3;                      // role
    const int lane = tid & 63, wave = tid >> 6;  // 4 waves

    // ---- publish my XCD; verify all 20 group members share it
    if (tid == 0)
        __hip_atomic_store(xcdA + blk, xcc_id() + 1u,
                           __ATOMIC_RELAXED, __HIP_MEMORY_SCOPE_AGENT);
    if (wave == 0) {
        unsigned v = 1u;
        for (;;) {
            if (lane < ROLES)
                v = coh_loadu(xcdA + (lane * NGRP + g));
            if (__all(v != 0)) break;
            __builtin_amdgcn_s_sleep(1);
        }
        unsigned ref = __shfl(v, 0, 64);
        int ok = __all(lane >= ROLES || v == ref);
        if (lane == 0) sLocalOK = ok;
    }

    unsigned* gC = gcnt + (long)g * NT;
    unsigned* pC = pcnt + (long)g * NT;
    const size_t HSZ = (size_t)NB * KH;           // elements per h slot
    const int m = lane & 15, quad = lane >> 4;

    if (c < NCOLB) {
        // ================= GEMM worker (4 waves x 32 rows) =================
        const int rbase = g * 128 + wave * 32;   // tile0: rbase+m, tile1: +16
        const int rowA0 = rbase + m;
        const int rowA1 = rbase + 16 + m;
        const int hcOut = c * 16 + m;            // < 304 <= HP, always valid addr
        const bool colOK = (hcOut < NH);

        float bias[4] = {0.f, 0.f, 0.f, 0.f};
        if (colOK) {
#pragma unroll
            for (int gt = 0; gt < 4; ++gt) bias[gt] = bl[gt * NH + hcOut];
        }
        float cst[2][4] = {};

        // ---- ALL 48 B fragments direct global -> VGPRs (once; 192 VGPRs).
        // Frag (kk,gt): WpT[(gt*HP + hcOut)*KT + kk*32 + quad*8 ..+8]
        bf16x8 B[12][4];
#pragma unroll
        for (int kk = 0; kk < 12; ++kk)
#pragma unroll
            for (int gt = 0; gt < 4; ++gt) {
                B[kk][gt] = *(const bf16x8*)(WpT + ((long)(gt * HP + hcOut) * KT)
                                             + kk * 32 + quad * 8);
                asm volatile("" : "+v"(B[kk][gt]));
            }

        __syncthreads();                         // sLocalOK visible
        const bool localOK = (sLocalOK != 0);

        for (int t = 0; t < NT; ++t) {
            // x fragments + x-part MFMAs BEFORE the wait (no h dependency)
            const bf16x8* xv0 = (const bf16x8*)(Xp + ((long)t * NB + rowA0) * KX);
            const bf16x8* xv1 = (const bf16x8*)(Xp + ((long)t * NB + rowA1) * KX);
            bf16x8 ax0[2], ax1[2];
#pragma unroll
            for (int kk = 0; kk < 2; ++kk) {
                ax0[kk] = xv0[kk * 4 + quad];
                ax1[kk] = xv1[kk * 4 + quad];
            }

            f32x4 acc[2][4];
#pragma unroll
            for (int rt = 0; rt < 2; ++rt)
#pragma unroll
                for (int gt = 0; gt < 4; ++gt)
                    acc[rt][gt] = (f32x4){bias[gt], bias[gt], bias[gt], bias[gt]};
#pragma unroll
            for (int kk = 0; kk < 2; ++kk) {
#pragma unroll
                for (int gt = 0; gt < 4; ++gt) {
                    acc[0][gt] = __builtin_amdgcn_mfma_f32_16x16x32_bf16(ax0[kk], B[kk][gt], acc[0][gt], 0, 0, 0);
                    acc[1][gt] = __builtin_amdgcn_mfma_f32_16x16x32_bf16(ax1[kk], B[kk][gt], acc[1][gt], 0, 0, 0);
                }
            }

            // wait: gcnt[t-1]==19 (h complete) and pcnt[t-8]>=1 (slot free)
            if (t > 0) {
                if (wave == 0) {
                    unsigned* gcp = gC + (t - 1);
                    unsigned* pcp = pC + (t - HSLOTS);
                    const bool needP = (t >= HSLOTS);
                    for (;;) {
                        unsigned v = 19u;
                        if (lane == 0)               v = coh_loadu(gcp);
                        else if (lane == 1 && needP) v = 18u + coh_loadu(pcp);
                        if (__all(v >= 19u)) break;
                        __builtin_amdgcn_s_sleep(1);
                    }
                    if (localOK) inv_l1();       // fence: fresh L2 view for h
                }
            }
            __syncthreads();
            __builtin_amdgcn_sched_barrier(0);

            const bf16_t* Hr = Hbase + (size_t)((t + HSLOTS - 1) & (HSLOTS - 1)) * HSZ;
            bf16_t*       Hw = Hbase + (size_t)(t & (HSLOTS - 1)) * HSZ;

            // ---- h A-fragments (both row tiles)
            const bf16_t* h0p = Hr + (long)rowA0 * KH;
            const bf16_t* h1p = Hr + (long)rowA1 * KH;
            bf16x8 ah0[10], ah1[10];
            if (localOK) {
                const bf16x8* hv0 = (const bf16x8*)h0p;
                const bf16x8* hv1 = (const bf16x8*)h1p;
#pragma unroll
                for (int i = 0; i < 10; ++i) {
                    ah0[i] = hv0[i * 4 + quad];
                    ah1[i] = hv1[i * 4 + quad];
                }
            } else {
#pragma unroll
                for (int i = 0; i < 10; ++i) {
                    ah0[i] = coh_load8(h0p + (i * 4 + quad) * 8);
                    ah1[i] = coh_load8(h1p + (i * 4 + quad) * 8);
                }
            }
            __builtin_amdgcn_sched_barrier(0);

            // h part: k-chunks 2..11, all B from registers (zero LDS)
#pragma unroll
            for (int kk = 2; kk < 12; ++kk) {
#pragma unroll
                for (int gt = 0; gt < 4; ++gt) {
                    acc[0][gt] = __builtin_amdgcn_mfma_f32_16x16x32_bf16(ah0[kk - 2], B[kk][gt], acc[0][gt], 0, 0, 0);
                    acc[1][gt] = __builtin_amdgcn_mfma_f32_16x16x32_bf16(ah1[kk - 2], B[kk][gt], acc[1][gt], 0, 0, 0);
                }
            }

            // ---- gates + state update + h store (C/D: col=m, row=quad*4+r)
#pragma unroll
            for (int rt = 0; rt < 2; ++rt) {
#pragma unroll
                for (int r = 0; r < 4; ++r) {
                    float zi = acc[rt][0][r];
                    float zj = acc[rt][1][r];
                    float zf = acc[rt][2][r];
                    float zo = acc[rt][3][r];
                    float cn = cst[rt][r] * fsig(zf + 1.0f) + fsig(zi) * ftanh(zj);
                    cst[rt][r] = cn;
                    float hn = ftanh(cn) * fsig(zo);
                    if (colOK) {
                        bf16_t* dst = Hw + (long)(rbase + rt * 16 + quad * 4 + r) * KH + hcOut;
                        if (localOK) *dst = (bf16_t)hn;
                        else coh_store16(dst, (bf16_t)hn);
                    }
                }
            }

            __syncthreads();   // all waves' h stores drained (vmcnt 0 at barrier)
            if (tid == 0) cnt_bump(gC + t);
        }
    } else {
        // ================= pred block: out[t] = h_t @ U + b2 via MFMA =========
        // U split into bf16 hi + lo (U = hi + lo) -> two MFMA accumulations.
        bf16_t* UThi = (bf16_t*)smem;                 // 16*320*2 = 10240 B
        bf16_t* UTlo = (bf16_t*)(smem + 10240);       // 10240 B
        for (int i = tid; i < 16 * 320; i += 256) {
            int n = i / 320, k = i % 320;
            float v = (n < 5 && k < NH) ? U[k * 5 + n] : 0.0f;
            bf16_t hi = (bf16_t)v;
            UThi[i] = hi;
            UTlo[i] = (bf16_t)(v - (float)hi);
        }
        const float b2v = (m < 5) ? b2[m] : 0.0f;
        __syncthreads();
        const bool localOK = (sLocalOK != 0);

        bf16x8 Bu[10][2];
#pragma unroll
        for (int kk = 0; kk < 10; ++kk) {
            Bu[kk][0] = *(const bf16x8*)(UThi + m * 320 + kk * 32 + quad * 8);
            asm volatile("" : "+v"(Bu[kk][0]));
            Bu[kk][1] = *(const bf16x8*)(UTlo + m * 320 + kk * 32 + quad * 8);
            asm volatile("" : "+v"(Bu[kk][1]));
        }
        const int rbase = g * 128 + wave * 32;        // 2 row tiles per wave
        const int row0 = rbase + m;
        const int row1 = rbase + 16 + m;

        for (int t = 0; t < NT; ++t) {
            if (wave == 0) {
                unsigned* gcp = gC + t;
                for (;;) {
                    unsigned v = 19u;
                    if (lane == 0) v = coh_loadu(gcp);
                    if (__all(v >= 19u)) break;
                    __builtin_amdgcn_s_sleep(1);
                }
                if (localOK) inv_l1();
            }
            __syncthreads();
            __builtin_amdgcn_sched_barrier(0);

            const bf16_t* Hs = Hbase + (size_t)(t & (HSLOTS - 1)) * HSZ;
            const bf16_t* h0p = Hs + (long)row0 * KH;
            const bf16_t* h1p = Hs + (long)row1 * KH;
            bf16x8 ah0[10], ah1[10];
            if (localOK) {
                const bf16x8* hv0 = (const bf16x8*)h0p;
                const bf16x8* hv1 = (const bf16x8*)h1p;
#pragma unroll
                for (int i = 0; i < 10; ++i) {
                    ah0[i] = hv0[i * 4 + quad];
                    ah1[i] = hv1[i * 4 + quad];
                }
            } else {
#pragma unroll
                for (int i = 0; i < 10; ++i) {
                    ah0[i] = coh_load8(h0p + (i * 4 + quad) * 8);
                    ah1[i] = coh_load8(h1p + (i * 4 + quad) * 8);
                }
            }
            __builtin_amdgcn_sched_barrier(0);

            f32x4 acc0 = (f32x4){0.f, 0.f, 0.f, 0.f};
            f32x4 acc1 = (f32x4){0.f, 0.f, 0.f, 0.f};
#pragma unroll
            for (int kk = 0; kk < 10; ++kk) {
                acc0 = __builtin_amdgcn_mfma_f32_16x16x32_bf16(ah0[kk], Bu[kk][0], acc0, 0, 0, 0);
                acc0 = __builtin_amdgcn_mfma_f32_16x16x32_bf16(ah0[kk], Bu[kk][1], acc0, 0, 0, 0);
                acc1 = __builtin_amdgcn_mfma_f32_16x16x32_bf16(ah1[kk], Bu[kk][0], acc1, 0, 0, 0);
                acc1 = __builtin_amdgcn_mfma_f32_16x16x32_bf16(ah1[kk], Bu[kk][1], acc1, 0, 0, 0);
            }

            // C/D: col = lane&15 (= class m, valid m<5), row = quad*4 + r
            if (m < 5) {
#pragma unroll
                for (int r = 0; r < 4; ++r) {
                    int ro0 = rbase + quad * 4 + r;
                    int ro1 = rbase + 16 + quad * 4 + r;
                    out[(long)t * (NB * 5) + ro0 * 5 + m] = acc0[r] + b2v;
                    out[(long)t * (NB * 5) + ro1 * 5 + m] = acc1[r] + b2v;
                }
            }

            __syncthreads();   // all waves' h reads of slot t&7 complete
            if (tid == 0) cnt_bump(pC + t);
        }
    }
}

// ---------------- launcher ----------------
extern "C" void kernel_launch(void* const* d_in, const int* in_sizes, int n_in,
                              void* d_out, int out_size, void* d_ws, size_t ws_size,
                              hipStream_t stream) {
    const int* ids   = (const int*)d_in[0];
    const float* emb = (const float*)d_in[1];
    const float* W   = (const float*)d_in[2];
    const float* bl  = (const float*)d_in[3];
    const float* U   = (const float*)d_in[4];
    const float* b2  = (const float*)d_in[5];
    float* out = (float*)d_out;

    // ws layout (16B-aligned, ~22 MB):
    //   WpT   0         ..   983,040   (4*320*384*2)
    //   H[8]  983,040   .. 6,225,920   (8*1024*320*2)
    //   gcnt  6,225,920 .. 6,229,760   (8*120*4)
    //   pcnt  6,229,760 .. 6,233,600   (8*120*4)
    //   xcdA  6,233,600 .. 6,234,240   (160*4)
    //   Xp    6,234,240 .. 21,962,880  (120*1024*64*2)
    char* ws = (char*)d_ws;
    bf16_t*   WpT   = (bf16_t*)ws;
    bf16_t*   Hbase = (bf16_t*)(ws + 983040);
    unsigned* gcnt  = (unsigned*)(ws + 6225920);
    unsigned* pcnt  = (unsigned*)(ws + 6229760);
    unsigned* xcdA  = (unsigned*)(ws + 6233600);
    bf16_t*   Xp    = (bf16_t*)(ws + 6234240);

    // one fused prep launch: zero H/gcnt/pcnt/xcdA (328,200 uint4 =
    // 5,251,200 B), pack W, gather embeddings
    prep_all<<<2048, 256, 0, stream>>>(ids, emb, W, WpT,
                                       (uint4*)(ws + 983040), 328200, Xp);

    void* kargs[] = { (void*)&bl, (void*)&WpT, (void*)&Hbase, (void*)&Xp,
                      (void*)&gcnt, (void*)&pcnt, (void*)&xcdA,
                      (void*)&U, (void*)&b2, (void*)&out };
    hipError_t err = hipLaunchCooperativeKernel((const void*)lstm_persist,
                                                dim3(GRID), dim3(256), kargs, 0, stream);
    if (err != hipSuccess) {
        // co-residency holds anyway: 160 blocks <= 256 CUs, ~20 KB LDS
        lstm_persist<<<GRID, 256, 0, stream>>>(bl, WpT, Hbase, Xp,
                                               gcnt, pcnt, xcdA, U, b2, out);
    }
}